// Round 10
// baseline (10668.457 us; speedup 1.0000x reference)
//
#include <hip/hip_runtime.h>
#include <cstdint>
#include <cstddef>

#define N_NODES_C 100000
#define N_EDGES_C 1250000
#define N_PAIRS_C 200000
#define IN_DIM_C 128
#define HID_C 64

// graph-build geometry
#define NB_S 256
#define BSH 9
#define NPB 512
#define NBKT 196
#define SEG_CAP 8192

// ---------------- scan helpers ----------------

#define SCAN_TPB 256
#define SCAN_IPT 4
#define SCAN_ELEMS 1024

__global__ void k_scan_partial(const int* __restrict__ in, int* __restrict__ outp,
                               int* __restrict__ blocksums, int n) {
    __shared__ int sd[SCAN_TPB];
    int tid = threadIdx.x;
    int base = blockIdx.x * SCAN_ELEMS + tid * SCAN_IPT;
    int v[SCAN_IPT]; int s = 0;
    for (int k = 0; k < SCAN_IPT; k++) { int idx = base + k; v[k] = (idx < n) ? in[idx] : 0; s += v[k]; }
    sd[tid] = s;
    __syncthreads();
    for (int off = 1; off < SCAN_TPB; off <<= 1) {
        int t = (tid >= off) ? sd[tid - off] : 0;
        __syncthreads();
        sd[tid] += t;
        __syncthreads();
    }
    int excl = sd[tid] - s;
    for (int k = 0; k < SCAN_IPT; k++) { int idx = base + k; if (idx < n) outp[idx] = excl; excl += v[k]; }
    if (tid == SCAN_TPB - 1) blocksums[blockIdx.x] = sd[tid];
}

__global__ void k_scan_blocks(int* __restrict__ bs, int nb) {
    __shared__ int sd[128];
    int t = threadIdx.x;
    int v = (t < nb) ? bs[t] : 0;
    sd[t] = v;
    __syncthreads();
    for (int off = 1; off < 128; off <<= 1) {
        int u = (t >= off) ? sd[t - off] : 0;
        __syncthreads();
        sd[t] += u;
        __syncthreads();
    }
    if (t < nb) bs[t] = sd[t] - v;
}

__global__ void k_scan_addg(int* __restrict__ arr, const int* __restrict__ bs, int n) {
    int i = blockIdx.x * blockDim.x + threadIdx.x;
    if (i < n) arr[i] += bs[i >> 10];
}

// ---------------- graph build: two-level counting sort ----------------

__global__ __launch_bounds__(256) void k_hist(const int* __restrict__ dst,
                                              int* __restrict__ histT, int e) {
    __shared__ int lh[NBKT];
    int tid = threadIdx.x, k = blockIdx.x;
    if (tid < NBKT) lh[tid] = 0;
    __syncthreads();
    int chunk = (e + NB_S - 1) / NB_S;
    int i0 = k * chunk, i1 = min(i0 + chunk, e);
    for (int i = i0 + tid; i < i1; i += 256) atomicAdd(&lh[dst[i] >> BSH], 1);
    __syncthreads();
    if (tid < NBKT) histT[tid * NB_S + k] = lh[tid];
}

__global__ __launch_bounds__(256) void k_scatter(const int* __restrict__ edges,
                                                 const int* __restrict__ offs,
                                                 int2* __restrict__ staging, int e) {
    __shared__ int cur[NBKT];
    int tid = threadIdx.x, k = blockIdx.x;
    if (tid < NBKT) cur[tid] = offs[tid * NB_S + k];
    __syncthreads();
    int chunk = (e + NB_S - 1) / NB_S;
    int i0 = k * chunk, i1 = min(i0 + chunk, e);
    for (int i = i0 + tid; i < i1; i += 256) {
        int s = edges[i];
        int d = edges[e + i];
        int p = atomicAdd(&cur[d >> BSH], 1);
        staging[p] = make_int2(s, d);
    }
}

__global__ __launch_bounds__(256) void k_bucket_fill(const int2* __restrict__ staging,
        const int* __restrict__ offs, int* __restrict__ rowptr,
        float* __restrict__ invd, int* __restrict__ adj, int n, int e) {
    __shared__ int ldeg[NPB];
    __shared__ int lrow[NPB];
    __shared__ int ps[256];
    __shared__ int lseg[SEG_CAP];
    int tid = threadIdx.x, b = blockIdx.x;
    int n0 = b << BSH;
    int nn = min(NPB, n - n0);
    int segBeg = offs[b * NB_S];
    int segEnd = (b == NBKT - 1) ? e : offs[(b + 1) * NB_S];

    ldeg[tid] = 0; ldeg[tid + 256] = 0;
    __syncthreads();
    for (int i = segBeg + tid; i < segEnd; i += 256)
        atomicAdd(&ldeg[staging[i].y - n0], 1);
    __syncthreads();

    int a0 = ldeg[2 * tid], a1 = ldeg[2 * tid + 1];
    int s = a0 + a1;
    ps[tid] = s;
    __syncthreads();
    for (int off = 1; off < 256; off <<= 1) {
        int t = (tid >= off) ? ps[tid - off] : 0;
        __syncthreads();
        ps[tid] += t;
        __syncthreads();
    }
    int excl = ps[tid] - s;
    lrow[2 * tid] = excl;
    lrow[2 * tid + 1] = excl + a0;
    __syncthreads();

    for (int j = tid; j < nn; j += 256) {
        rowptr[n0 + j] = segBeg + lrow[j];
        int d = ldeg[j];
        invd[n0 + j] = (d > 0) ? (1.0f / (float)d) : 0.0f;
    }
    if (b == NBKT - 1 && tid == 0) rowptr[n] = e;
    __syncthreads();

    for (int i = segBeg + tid; i < segEnd; i += 256) {
        int2 ed = staging[i];
        int p = atomicAdd(&lrow[ed.y - n0], 1);
        if (p < SEG_CAP) lseg[p] = ed.x;
        else adj[segBeg + p] = ed.x;
    }
    __syncthreads();

    int m = segEnd - segBeg; if (m > SEG_CAP) m = SEG_CAP;
    for (int p = tid; p < m; p += 256) adj[segBeg + p] = lseg[p];
}

// ---------------- aggregation ----------------

__global__ __launch_bounds__(256) void k_aggregate(const int* __restrict__ rowptr,
        const int* __restrict__ adj, const float* __restrict__ invd,
        const float* __restrict__ hin, float* __restrict__ agg, int n) {
    int wid = threadIdx.x >> 6, lane = threadIdx.x & 63;
    int node = blockIdx.x * 4 + wid;
    if (node >= n) return;
    int beg = rowptr[node], end = rowptr[node + 1];
    float acc = 0.0f;
    for (int e = beg; e < end; e += 8) {
        int idx[8];
        #pragma unroll
        for (int j = 0; j < 8; ++j) {
            int ee = e + j;
            idx[j] = adj[ee < end ? ee : end - 1];
        }
        float v[8];
        #pragma unroll
        for (int j = 0; j < 8; ++j) v[j] = hin[(size_t)idx[j] * HID_C + lane];
        #pragma unroll
        for (int j = 0; j < 8; ++j) acc += (e + j < end) ? v[j] : 0.0f;
    }
    agg[(size_t)node * HID_C + lane] = acc * invd[node];
}

// ------- LDS-staged GEMM: R8 structure, launch_bounds(256,2) probe ----------
// SINGLE-VARIABLE CHANGE vs R8: __launch_bounds__ 2nd arg 3 -> 2.
// REGISTER-SPLIT RULE (R4-R9 failure matrix): on this hipcc/gfx950, a
// launch_bounds waves-per-EU arg w>=3 halves the usable VGPR budget
// (measured VGPR = (512/w)/2 exactly: w=3 -> 84, w=4 -> 64) and spills the
// rest to scratch (1.5-6.3 GB HBM traffic/dispatch, VALUBusy ~1%).
// KEEP w<=2 ALWAYS. Occupancy comes from the LDS footprint instead:
// 32 KB (W) + 16 KB (AT, one 64-K half) = 48 KB -> HW schedules 3 blocks/CU.
// AT layout: k-major, no swizzle: A[r][k] at AT[(k>>2)*256 + (k&3)*64 + r].
//  - staging lane-row-major (lane = row): write banks = r%32, 2-way (free)
//  - compute read: 4 distinct b128 quads + 16-lane broadcast -> conflict-free
// Inner loop: R4-verbatim fmaf chains (plain named locals only).
// MODE 0: encoder  MODE 1: layer  MODE 2: pred (fused @W2+b2)

__device__ __forceinline__ float4 ld4(const float* p) { return *(const float4*)p; }

template<int MODE>
__global__ __launch_bounds__(256, 2) void k_gemm(
    const float* __restrict__ A1, const float* __restrict__ A2,
    const int* __restrict__ pidx,
    const float* __restrict__ Ws1, const float* __restrict__ Ws2,
    const float* __restrict__ bias, const float* __restrict__ W2p,
    const float* __restrict__ b2p,
    float* __restrict__ outp, int nrows)
{
    __shared__ float Wm[128 * 64];   // 32 KB, k-major
    __shared__ float AT[64 * 64];    // 16 KB, one K-half
    const int t = threadIdx.x;
    const int g0 = blockIdx.x * 64;

    // stage W (K=128)
    #pragma unroll
    for (int p = 0; p < 8; ++p) {
        int k = p * 16 + (t >> 4);
        int c4 = (t & 15) * 4;
        float4 wv;
        if (MODE == 1) wv = (k < 64) ? ld4(Ws1 + k * 64 + c4) : ld4(Ws2 + (k - 64) * 64 + c4);
        else           wv = ld4(Ws1 + k * 64 + c4);
        *(float4*)&Wm[k * 64 + c4] = wv;
    }

    const int tc = t & 15, tr = t >> 4;
    const int tc4 = tc * 4, tr4 = tr * 4;
    const int srow = t & 63;          // staging: lane = row
    const int scw  = t >> 6;          // staging: chunk-column group (0..3)

    float4 acc0 = {0, 0, 0, 0}, acc1 = acc0, acc2 = acc0, acc3 = acc0;

    #pragma unroll
    for (int H = 0; H < 2; ++H) {
        if (H) __syncthreads();       // protect AT before re-staging
        // stage A half H: thread = row srow, chunks scw+4q (q=0..3)
        {
            int g = g0 + srow; if (g > nrows - 1) g = nrows - 1;
            const float* rowp;
            if (MODE == 0)      rowp = A1 + (size_t)g * 128 + H * 64;
            else if (MODE == 1) rowp = (H == 0 ? A1 : A2) + (size_t)g * 64;
            else { int idx = pidx[2 * g + H]; rowp = A1 + (size_t)idx * 64; }
            #pragma unroll
            for (int q = 0; q < 4; ++q) {
                int c = scw + 4 * q;
                float4 av = ld4(rowp + c * 4);
                int base = c * 256 + srow;
                AT[base      ] = av.x;
                AT[base +  64] = av.y;
                AT[base + 128] = av.z;
                AT[base + 192] = av.w;
            }
        }
        __syncthreads();
        // compute half H — R4 inner loop verbatim
        #pragma unroll
        for (int kc = 0; kc < 16; ++kc) {
            int abase = kc * 256 + tr4;
            int wbase = (H * 64 + 4 * kc) * 64 + tc4;
            #pragma unroll
            for (int i = 0; i < 4; ++i) {
                float4 aw = ld4(&AT[abase + i * 64]);
                float4 ww = ld4(&Wm[wbase + i * 64]);
                acc0.x = fmaf(aw.x, ww.x, acc0.x); acc0.y = fmaf(aw.x, ww.y, acc0.y);
                acc0.z = fmaf(aw.x, ww.z, acc0.z); acc0.w = fmaf(aw.x, ww.w, acc0.w);
                acc1.x = fmaf(aw.y, ww.x, acc1.x); acc1.y = fmaf(aw.y, ww.y, acc1.y);
                acc1.z = fmaf(aw.y, ww.z, acc1.z); acc1.w = fmaf(aw.y, ww.w, acc1.w);
                acc2.x = fmaf(aw.z, ww.x, acc2.x); acc2.y = fmaf(aw.z, ww.y, acc2.y);
                acc2.z = fmaf(aw.z, ww.z, acc2.z); acc2.w = fmaf(aw.z, ww.w, acc2.w);
                acc3.x = fmaf(aw.w, ww.x, acc3.x); acc3.y = fmaf(aw.w, ww.y, acc3.y);
                acc3.z = fmaf(aw.w, ww.z, acc3.z); acc3.w = fmaf(aw.w, ww.w, acc3.w);
            }
        }
    }

    float4 bv = ld4(bias + tc4);
    float4 accs[4] = {acc0, acc1, acc2, acc3};
    if (MODE == 2) {
        float4 w2 = ld4(W2p + tc4);
        float bb = b2p[0];
        #pragma unroll
        for (int i = 0; i < 4; ++i) {
            float zx = fmaxf(accs[i].x + bv.x, 0.f);
            float zy = fmaxf(accs[i].y + bv.y, 0.f);
            float zz = fmaxf(accs[i].z + bv.z, 0.f);
            float zw = fmaxf(accs[i].w + bv.w, 0.f);
            float v = zx * w2.x + zy * w2.y + zz * w2.z + zw * w2.w;
            v += __shfl_down(v, 8, 64);
            v += __shfl_down(v, 4, 64);
            v += __shfl_down(v, 2, 64);
            v += __shfl_down(v, 1, 64);
            if (tc == 0) {
                int g = g0 + tr4 + i;
                if (g < nrows) outp[g] = v + bb;
            }
        }
    } else {
        #pragma unroll
        for (int i = 0; i < 4; ++i) {
            int g = g0 + tr4 + i;
            if (g < nrows) {
                float4 o;
                o.x = fmaxf(accs[i].x + bv.x, 0.f);
                o.y = fmaxf(accs[i].y + bv.y, 0.f);
                o.z = fmaxf(accs[i].z + bv.z, 0.f);
                o.w = fmaxf(accs[i].w + bv.w, 0.f);
                *(float4*)&outp[(size_t)g * 64 + tc4] = o;
            }
        }
    }
}

// ---------------- launch ----------------

extern "C" void kernel_launch(void* const* d_in, const int* in_sizes, int n_in,
                              void* d_out, int out_size, void* d_ws, size_t ws_size,
                              hipStream_t stream) {
    const float* x    = (const float*)d_in[0];
    const int*   edges= (const int*)d_in[1];
    const int*   pair = (const int*)d_in[2];
    const float* encW = (const float*)d_in[3];
    const float* encb = (const float*)d_in[4];
    const float* Wl   = (const float*)d_in[5];
    const float* bl   = (const float*)d_in[6];
    const float* Wr   = (const float*)d_in[7];
    const float* W1   = (const float*)d_in[8];
    const float* b1   = (const float*)d_in[9];
    const float* W2   = (const float*)d_in[10];
    const float* b2   = (const float*)d_in[11];
    float* out = (float*)d_out;

    const int N = N_NODES_C, E = N_EDGES_C, P = N_PAIRS_C;
    const int* dst = edges + E;
    const int M = NBKT * NB_S;

    char* w = (char*)d_ws;
    auto alloc = [&](size_t bytes) { char* p = w; w += (bytes + 255) & ~(size_t)255; return p; };
    int*   rowptr = (int*)alloc((size_t)(N + 1) * 4);
    int*   histT  = (int*)alloc((size_t)M * 4);
    int*   offs   = (int*)alloc((size_t)M * 4);
    int*   bsums  = (int*)alloc(128 * 4);
    float* invd   = (float*)alloc((size_t)N * 4);
    int*   adj    = (int*)alloc((size_t)E * 4);
    float* h0     = (float*)alloc((size_t)N * HID_C * 4);
    float* h1     = (float*)alloc((size_t)N * HID_C * 4);
    float* agg    = (float*)alloc((size_t)N * HID_C * 4);
    int2*  staging= (int2*)agg;

    int nscan = (M + SCAN_ELEMS - 1) / SCAN_ELEMS;

    hipLaunchKernelGGL(k_hist, dim3(NB_S), dim3(256), 0, stream, dst, histT, E);
    hipLaunchKernelGGL(k_scan_partial, dim3(nscan), dim3(SCAN_TPB), 0, stream, histT, offs, bsums, M);
    hipLaunchKernelGGL(k_scan_blocks, dim3(1), dim3(128), 0, stream, bsums, nscan);
    hipLaunchKernelGGL(k_scan_addg, dim3((M + 255) / 256), dim3(256), 0, stream, offs, bsums, M);
    hipLaunchKernelGGL(k_scatter, dim3(NB_S), dim3(256), 0, stream, edges, offs, staging, E);
    hipLaunchKernelGGL(k_bucket_fill, dim3(NBKT), dim3(256), 0, stream, staging, offs, rowptr, invd, adj, N, E);

    const int NB_N = (N + 63) / 64;
    const int NB_P = (P + 63) / 64;

    k_gemm<0><<<dim3(NB_N), dim3(256), 0, stream>>>(
        x, nullptr, nullptr, encW, nullptr, encb, nullptr, nullptr, h0, N);

    float* hc = h0; float* hn = h1;
    for (int l = 0; l < 3; l++) {
        hipLaunchKernelGGL(k_aggregate, dim3((N + 3) / 4), dim3(256), 0, stream,
                           rowptr, adj, invd, hc, agg, N);
        k_gemm<1><<<dim3(NB_N), dim3(256), 0, stream>>>(
            agg, hc, nullptr, Wl + (size_t)l * 64 * 64, Wr + (size_t)l * 64 * 64,
            bl + (size_t)l * 64, nullptr, nullptr, hn, N);
        float* tswap = hc; hc = hn; hn = tswap;
    }

    k_gemm<2><<<dim3(NB_P), dim3(256), 0, stream>>>(
        hc, nullptr, pair, W1, nullptr, b1, W2, b2, out, P);
}

// Round 11
// 500.544 us; speedup vs baseline: 21.3137x; 21.3137x over previous
//
#include <hip/hip_runtime.h>
#include <cstdint>
#include <cstddef>

#define N_NODES_C 100000
#define N_EDGES_C 1250000
#define N_PAIRS_C 200000
#define IN_DIM_C 128
#define HID_C 64

// graph-build geometry
#define NB_S 256
#define BSH 9
#define NPB 512
#define NBKT 196
#define SEG_CAP 8192

// ---------------- scan helpers ----------------

#define SCAN_TPB 256
#define SCAN_IPT 4
#define SCAN_ELEMS 1024

__global__ void k_scan_partial(const int* __restrict__ in, int* __restrict__ outp,
                               int* __restrict__ blocksums, int n) {
    __shared__ int sd[SCAN_TPB];
    int tid = threadIdx.x;
    int base = blockIdx.x * SCAN_ELEMS + tid * SCAN_IPT;
    int v[SCAN_IPT]; int s = 0;
    for (int k = 0; k < SCAN_IPT; k++) { int idx = base + k; v[k] = (idx < n) ? in[idx] : 0; s += v[k]; }
    sd[tid] = s;
    __syncthreads();
    for (int off = 1; off < SCAN_TPB; off <<= 1) {
        int t = (tid >= off) ? sd[tid - off] : 0;
        __syncthreads();
        sd[tid] += t;
        __syncthreads();
    }
    int excl = sd[tid] - s;
    for (int k = 0; k < SCAN_IPT; k++) { int idx = base + k; if (idx < n) outp[idx] = excl; excl += v[k]; }
    if (tid == SCAN_TPB - 1) blocksums[blockIdx.x] = sd[tid];
}

__global__ void k_scan_blocks(int* __restrict__ bs, int nb) {
    __shared__ int sd[128];
    int t = threadIdx.x;
    int v = (t < nb) ? bs[t] : 0;
    sd[t] = v;
    __syncthreads();
    for (int off = 1; off < 128; off <<= 1) {
        int u = (t >= off) ? sd[t - off] : 0;
        __syncthreads();
        sd[t] += u;
        __syncthreads();
    }
    if (t < nb) bs[t] = sd[t] - v;
}

__global__ void k_scan_addg(int* __restrict__ arr, const int* __restrict__ bs, int n) {
    int i = blockIdx.x * blockDim.x + threadIdx.x;
    if (i < n) arr[i] += bs[i >> 10];
}

// ---------------- graph build: two-level counting sort ----------------

__global__ __launch_bounds__(256) void k_hist(const int* __restrict__ dst,
                                              int* __restrict__ histT, int e) {
    __shared__ int lh[NBKT];
    int tid = threadIdx.x, k = blockIdx.x;
    if (tid < NBKT) lh[tid] = 0;
    __syncthreads();
    int chunk = (e + NB_S - 1) / NB_S;
    int i0 = k * chunk, i1 = min(i0 + chunk, e);
    for (int i = i0 + tid; i < i1; i += 256) atomicAdd(&lh[dst[i] >> BSH], 1);
    __syncthreads();
    if (tid < NBKT) histT[tid * NB_S + k] = lh[tid];
}

__global__ __launch_bounds__(256) void k_scatter(const int* __restrict__ edges,
                                                 const int* __restrict__ offs,
                                                 int2* __restrict__ staging, int e) {
    __shared__ int cur[NBKT];
    int tid = threadIdx.x, k = blockIdx.x;
    if (tid < NBKT) cur[tid] = offs[tid * NB_S + k];
    __syncthreads();
    int chunk = (e + NB_S - 1) / NB_S;
    int i0 = k * chunk, i1 = min(i0 + chunk, e);
    for (int i = i0 + tid; i < i1; i += 256) {
        int s = edges[i];
        int d = edges[e + i];
        int p = atomicAdd(&cur[d >> BSH], 1);
        staging[p] = make_int2(s, d);
    }
}

__global__ __launch_bounds__(256) void k_bucket_fill(const int2* __restrict__ staging,
        const int* __restrict__ offs, int* __restrict__ rowptr,
        float* __restrict__ invd, int* __restrict__ adj, int n, int e) {
    __shared__ int ldeg[NPB];
    __shared__ int lrow[NPB];
    __shared__ int ps[256];
    __shared__ int lseg[SEG_CAP];
    int tid = threadIdx.x, b = blockIdx.x;
    int n0 = b << BSH;
    int nn = min(NPB, n - n0);
    int segBeg = offs[b * NB_S];
    int segEnd = (b == NBKT - 1) ? e : offs[(b + 1) * NB_S];

    ldeg[tid] = 0; ldeg[tid + 256] = 0;
    __syncthreads();
    for (int i = segBeg + tid; i < segEnd; i += 256)
        atomicAdd(&ldeg[staging[i].y - n0], 1);
    __syncthreads();

    int a0 = ldeg[2 * tid], a1 = ldeg[2 * tid + 1];
    int s = a0 + a1;
    ps[tid] = s;
    __syncthreads();
    for (int off = 1; off < 256; off <<= 1) {
        int t = (tid >= off) ? ps[tid - off] : 0;
        __syncthreads();
        ps[tid] += t;
        __syncthreads();
    }
    int excl = ps[tid] - s;
    lrow[2 * tid] = excl;
    lrow[2 * tid + 1] = excl + a0;
    __syncthreads();

    for (int j = tid; j < nn; j += 256) {
        rowptr[n0 + j] = segBeg + lrow[j];
        int d = ldeg[j];
        invd[n0 + j] = (d > 0) ? (1.0f / (float)d) : 0.0f;
    }
    if (b == NBKT - 1 && tid == 0) rowptr[n] = e;
    __syncthreads();

    for (int i = segBeg + tid; i < segEnd; i += 256) {
        int2 ed = staging[i];
        int p = atomicAdd(&lrow[ed.y - n0], 1);
        if (p < SEG_CAP) lseg[p] = ed.x;
        else adj[segBeg + p] = ed.x;
    }
    __syncthreads();

    int m = segEnd - segBeg; if (m > SEG_CAP) m = SEG_CAP;
    for (int p = tid; p < m; p += 256) adj[segBeg + p] = lseg[p];
}

// ---------------- pair locality sort (for pred gather) ----------------

__global__ __launch_bounds__(256) void k_hist_p(const int* __restrict__ pr,
                                                int* __restrict__ histT, int p) {
    __shared__ int lh[NBKT];
    int tid = threadIdx.x, k = blockIdx.x;
    if (tid < NBKT) lh[tid] = 0;
    __syncthreads();
    int chunk = (p + NB_S - 1) / NB_S;
    int i0 = k * chunk, i1 = min(i0 + chunk, p);
    for (int i = i0 + tid; i < i1; i += 256) atomicAdd(&lh[pr[2 * i] >> BSH], 1);
    __syncthreads();
    if (tid < NBKT) histT[tid * NB_S + k] = lh[tid];
}

__global__ __launch_bounds__(256) void k_scatter_p(const int* __restrict__ pr,
        const int* __restrict__ offs, int2* __restrict__ sp,
        int* __restrict__ po, int p) {
    __shared__ int cur[NBKT];
    int tid = threadIdx.x, k = blockIdx.x;
    if (tid < NBKT) cur[tid] = offs[tid * NB_S + k];
    __syncthreads();
    int chunk = (p + NB_S - 1) / NB_S;
    int i0 = k * chunk, i1 = min(i0 + chunk, p);
    for (int i = i0 + tid; i < i1; i += 256) {
        int a = pr[2 * i], b = pr[2 * i + 1];
        int pos = atomicAdd(&cur[a >> BSH], 1);
        sp[pos] = make_int2(a, b);
        po[pos] = i;
    }
}

__global__ void k_unperm(const float* __restrict__ tmp, const int* __restrict__ po,
                         float* __restrict__ outp, int p) {
    int i = blockIdx.x * blockDim.x + threadIdx.x;
    if (i < p) outp[po[i]] = tmp[i];
}

// ---------------- aggregation (16-wide latency-hiding unroll) ----------------

__global__ __launch_bounds__(256) void k_aggregate(const int* __restrict__ rowptr,
        const int* __restrict__ adj, const float* __restrict__ invd,
        const float* __restrict__ hin, float* __restrict__ agg, int n) {
    int wid = threadIdx.x >> 6, lane = threadIdx.x & 63;
    int node = blockIdx.x * 4 + wid;
    if (node >= n) return;
    int beg = rowptr[node], end = rowptr[node + 1];
    float acc = 0.0f;
    for (int e = beg; e < end; e += 16) {
        int idx[16];
        #pragma unroll
        for (int j = 0; j < 16; ++j) {
            int ee = e + j;
            idx[j] = adj[ee < end ? ee : end - 1];
        }
        float v[16];
        #pragma unroll
        for (int j = 0; j < 16; ++j) v[j] = hin[(size_t)idx[j] * HID_C + lane];
        #pragma unroll
        for (int j = 0; j < 16; ++j) acc += (e + j < end) ? v[j] : 0.0f;
    }
    agg[(size_t)node * HID_C + lane] = acc * invd[node];
}

// ---------------- tiled GEMM (64 rows x 64 cols, K=128, thread = 4x4 tile) ----
// R4/R9 PROVEN ARTIFACT — byte-identical. 65 us pred GEMM, 44 MB fetch,
// VGPR 92, no scratch. Every structural deviation tried (R5-R10: register-
// direct A, two-half AT with in-loop barriers, any launch_bounds variation
// combined with those) triggered a hipcc scratch pathology (1.5-6.3 GB HBM
// traffic/dispatch, VALUBusy ~1%). DO NOT MODIFY THIS KERNEL.
// MODE 0: encoder  MODE 1: layer  MODE 2: pred (fused @W2+b2)

__device__ __forceinline__ float4 ld4(const float* p) { return *(const float4*)p; }

template<int MODE>
__global__ __launch_bounds__(256, 2) void k_gemm(
    const float* __restrict__ A1, const float* __restrict__ A2,
    const int* __restrict__ pidx,
    const float* __restrict__ Ws1, const float* __restrict__ Ws2,
    const float* __restrict__ bias, const float* __restrict__ W2p,
    const float* __restrict__ b2p,
    float* __restrict__ outp, int nrows)
{
    __shared__ float AT[128 * 64];   // 32 KB, transposed+swizzled
    __shared__ float Wm[128 * 64];   // 32 KB, k-major
    const int t = threadIdx.x;
    const int g0 = blockIdx.x * 64;

    #pragma unroll
    for (int p = 0; p < 8; ++p) {
        int k = p * 16 + (t >> 4);
        int c4 = (t & 15) * 4;
        float4 wv;
        if (MODE == 1) wv = (k < 64) ? ld4(Ws1 + k * 64 + c4) : ld4(Ws2 + (k - 64) * 64 + c4);
        else           wv = ld4(Ws1 + k * 64 + c4);
        *(float4*)&Wm[k * 64 + c4] = wv;
    }
    #pragma unroll
    for (int p = 0; p < 8; ++p) {
        int r = p * 8 + (t >> 5);
        int c = t & 31;
        int g = g0 + r; if (g > nrows - 1) g = nrows - 1;
        const float* ptr;
        if (MODE == 0)      ptr = A1 + (size_t)g * 128 + c * 4;
        else if (MODE == 1) ptr = (c < 16) ? (A1 + (size_t)g * 64 + c * 4)
                                           : (A2 + (size_t)g * 64 + (c - 16) * 4);
        else { int idx = pidx[2 * g + (c >> 4)]; ptr = A1 + (size_t)idx * 64 + (c & 15) * 4; }
        float4 av = ld4(ptr);
        int rs = r ^ ((c & 15) * 4);
        int base = c * 256 + rs;
        AT[base      ] = av.x;
        AT[base +  64] = av.y;
        AT[base + 128] = av.z;
        AT[base + 192] = av.w;
    }
    __syncthreads();

    const int tc = t & 15, tr = t >> 4;
    const int tc4 = tc * 4, tr4 = tr * 4;
    float4 acc0 = {0, 0, 0, 0}, acc1 = acc0, acc2 = acc0, acc3 = acc0;

    #pragma unroll 4
    for (int kc = 0; kc < 32; ++kc) {
        int abase = kc * 256 + (tr4 ^ ((kc & 15) * 4));
        int wbase = kc * 256 + tc4;
        #pragma unroll
        for (int i = 0; i < 4; ++i) {
            float4 aw = ld4(&AT[abase + i * 64]);
            float4 ww = ld4(&Wm[wbase + i * 64]);
            acc0.x = fmaf(aw.x, ww.x, acc0.x); acc0.y = fmaf(aw.x, ww.y, acc0.y);
            acc0.z = fmaf(aw.x, ww.z, acc0.z); acc0.w = fmaf(aw.x, ww.w, acc0.w);
            acc1.x = fmaf(aw.y, ww.x, acc1.x); acc1.y = fmaf(aw.y, ww.y, acc1.y);
            acc1.z = fmaf(aw.y, ww.z, acc1.z); acc1.w = fmaf(aw.y, ww.w, acc1.w);
            acc2.x = fmaf(aw.z, ww.x, acc2.x); acc2.y = fmaf(aw.z, ww.y, acc2.y);
            acc2.z = fmaf(aw.z, ww.z, acc2.z); acc2.w = fmaf(aw.z, ww.w, acc2.w);
            acc3.x = fmaf(aw.w, ww.x, acc3.x); acc3.y = fmaf(aw.w, ww.y, acc3.y);
            acc3.z = fmaf(aw.w, ww.z, acc3.z); acc3.w = fmaf(aw.w, ww.w, acc3.w);
        }
    }

    float4 bv = ld4(bias + tc4);
    float4 accs[4] = {acc0, acc1, acc2, acc3};
    if (MODE == 2) {
        float4 w2 = ld4(W2p + tc4);
        float bb = b2p[0];
        #pragma unroll
        for (int i = 0; i < 4; ++i) {
            float zx = fmaxf(accs[i].x + bv.x, 0.f);
            float zy = fmaxf(accs[i].y + bv.y, 0.f);
            float zz = fmaxf(accs[i].z + bv.z, 0.f);
            float zw = fmaxf(accs[i].w + bv.w, 0.f);
            float v = zx * w2.x + zy * w2.y + zz * w2.z + zw * w2.w;
            v += __shfl_down(v, 8, 64);
            v += __shfl_down(v, 4, 64);
            v += __shfl_down(v, 2, 64);
            v += __shfl_down(v, 1, 64);
            if (tc == 0) {
                int g = g0 + tr4 + i;
                if (g < nrows) outp[g] = v + bb;
            }
        }
    } else {
        #pragma unroll
        for (int i = 0; i < 4; ++i) {
            int g = g0 + tr4 + i;
            if (g < nrows) {
                float4 o;
                o.x = fmaxf(accs[i].x + bv.x, 0.f);
                o.y = fmaxf(accs[i].y + bv.y, 0.f);
                o.z = fmaxf(accs[i].z + bv.z, 0.f);
                o.w = fmaxf(accs[i].w + bv.w, 0.f);
                *(float4*)&outp[(size_t)g * 64 + tc4] = o;
            }
        }
    }
}

// ---------------- launch ----------------

extern "C" void kernel_launch(void* const* d_in, const int* in_sizes, int n_in,
                              void* d_out, int out_size, void* d_ws, size_t ws_size,
                              hipStream_t stream) {
    const float* x    = (const float*)d_in[0];
    const int*   edges= (const int*)d_in[1];
    const int*   pair = (const int*)d_in[2];
    const float* encW = (const float*)d_in[3];
    const float* encb = (const float*)d_in[4];
    const float* Wl   = (const float*)d_in[5];
    const float* bl   = (const float*)d_in[6];
    const float* Wr   = (const float*)d_in[7];
    const float* W1   = (const float*)d_in[8];
    const float* b1   = (const float*)d_in[9];
    const float* W2   = (const float*)d_in[10];
    const float* b2   = (const float*)d_in[11];
    float* out = (float*)d_out;

    const int N = N_NODES_C, E = N_EDGES_C, P = N_PAIRS_C;
    const int* dst = edges + E;
    const int M = NBKT * NB_S;

    char* w = (char*)d_ws;
    auto alloc = [&](size_t bytes) { char* p = w; w += (bytes + 255) & ~(size_t)255; return p; };
    int*   rowptr = (int*)alloc((size_t)(N + 1) * 4);
    int*   histT  = (int*)alloc((size_t)M * 4);
    int*   offs   = (int*)alloc((size_t)M * 4);
    int*   bsums  = (int*)alloc(128 * 4);
    float* invd   = (float*)alloc((size_t)N * 4);
    int*   adj    = (int*)alloc((size_t)E * 4);
    float* h0     = (float*)alloc((size_t)N * HID_C * 4);
    float* h1     = (float*)alloc((size_t)N * HID_C * 4);
    float* agg    = (float*)alloc((size_t)N * HID_C * 4);
    // aliases into agg's 25.6 MB region (temporally disjoint from agg use):
    int2*  staging= (int2*)agg;                      // graph build (before layers)
    int2*  sp     = (int2*)agg;                      // sorted pairs (after layers)
    int*   po     = (int*)((char*)agg + (size_t)P * 8);      // orig index
    float* ptmp   = (float*)((char*)agg + (size_t)P * 12);   // pred out (sorted order)

    int nscan = (M + SCAN_ELEMS - 1) / SCAN_ELEMS;

    // graph build
    hipLaunchKernelGGL(k_hist, dim3(NB_S), dim3(256), 0, stream, dst, histT, E);
    hipLaunchKernelGGL(k_scan_partial, dim3(nscan), dim3(SCAN_TPB), 0, stream, histT, offs, bsums, M);
    hipLaunchKernelGGL(k_scan_blocks, dim3(1), dim3(128), 0, stream, bsums, nscan);
    hipLaunchKernelGGL(k_scan_addg, dim3((M + 255) / 256), dim3(256), 0, stream, offs, bsums, M);
    hipLaunchKernelGGL(k_scatter, dim3(NB_S), dim3(256), 0, stream, edges, offs, staging, E);
    hipLaunchKernelGGL(k_bucket_fill, dim3(NBKT), dim3(256), 0, stream, staging, offs, rowptr, invd, adj, N, E);

    const int NB_N = (N + 63) / 64;
    const int NB_P = (P + 63) / 64;

    k_gemm<0><<<dim3(NB_N), dim3(256), 0, stream>>>(
        x, nullptr, nullptr, encW, nullptr, encb, nullptr, nullptr, h0, N);

    float* hc = h0; float* hn = h1;
    for (int l = 0; l < 3; l++) {
        hipLaunchKernelGGL(k_aggregate, dim3((N + 3) / 4), dim3(256), 0, stream,
                           rowptr, adj, invd, hc, agg, N);
        k_gemm<1><<<dim3(NB_N), dim3(256), 0, stream>>>(
            agg, hc, nullptr, Wl + (size_t)l * 64 * 64, Wr + (size_t)l * 64 * 64,
            bl + (size_t)l * 64, nullptr, nullptr, hn, N);
        float* tswap = hc; hc = hn; hn = tswap;
    }

    // pair locality sort (agg now dead; histT/offs reused)
    hipLaunchKernelGGL(k_hist_p, dim3(NB_S), dim3(256), 0, stream, pair, histT, P);
    hipLaunchKernelGGL(k_scan_partial, dim3(nscan), dim3(SCAN_TPB), 0, stream, histT, offs, bsums, M);
    hipLaunchKernelGGL(k_scan_blocks, dim3(1), dim3(128), 0, stream, bsums, nscan);
    hipLaunchKernelGGL(k_scan_addg, dim3((M + 255) / 256), dim3(256), 0, stream, offs, bsums, M);
    hipLaunchKernelGGL(k_scatter_p, dim3(NB_S), dim3(256), 0, stream, pair, offs, sp, po, P);

    k_gemm<2><<<dim3(NB_P), dim3(256), 0, stream>>>(
        hc, nullptr, (const int*)sp, W1, nullptr, b1, W2, b2, ptmp, P);
    hipLaunchKernelGGL(k_unperm, dim3((P + 255) / 256), dim3(256), 0, stream, ptmp, po, out, P);
}

// Round 12
// 466.235 us; speedup vs baseline: 22.8821x; 1.0736x over previous
//
#include <hip/hip_runtime.h>
#include <cstdint>
#include <cstddef>

#define N_NODES_C 100000
#define N_EDGES_C 1250000
#define N_PAIRS_C 200000
#define IN_DIM_C 128
#define HID_C 64

// graph-build geometry
#define NB_S 256
#define BSH 9
#define NPB 512
#define NBKT 196
#define SEG_CAP 8192

// ---------------- scan helpers ----------------

#define SCAN_TPB 256
#define SCAN_IPT 4
#define SCAN_ELEMS 1024

__global__ void k_scan_partial(const int* __restrict__ in, int* __restrict__ outp,
                               int* __restrict__ blocksums, int n) {
    __shared__ int sd[SCAN_TPB];
    int tid = threadIdx.x;
    int base = blockIdx.x * SCAN_ELEMS + tid * SCAN_IPT;
    int v[SCAN_IPT]; int s = 0;
    for (int k = 0; k < SCAN_IPT; k++) { int idx = base + k; v[k] = (idx < n) ? in[idx] : 0; s += v[k]; }
    sd[tid] = s;
    __syncthreads();
    for (int off = 1; off < SCAN_TPB; off <<= 1) {
        int t = (tid >= off) ? sd[tid - off] : 0;
        __syncthreads();
        sd[tid] += t;
        __syncthreads();
    }
    int excl = sd[tid] - s;
    for (int k = 0; k < SCAN_IPT; k++) { int idx = base + k; if (idx < n) outp[idx] = excl; excl += v[k]; }
    if (tid == SCAN_TPB - 1) blocksums[blockIdx.x] = sd[tid];
}

__global__ void k_scan_blocks(int* __restrict__ bs, int nb) {
    __shared__ int sd[128];
    int t = threadIdx.x;
    int v = (t < nb) ? bs[t] : 0;
    sd[t] = v;
    __syncthreads();
    for (int off = 1; off < 128; off <<= 1) {
        int u = (t >= off) ? sd[t - off] : 0;
        __syncthreads();
        sd[t] += u;
        __syncthreads();
    }
    if (t < nb) bs[t] = sd[t] - v;
}

__global__ void k_scan_addg(int* __restrict__ arr, const int* __restrict__ bs, int n) {
    int i = blockIdx.x * blockDim.x + threadIdx.x;
    if (i < n) arr[i] += bs[i >> 10];
}

// ---------------- graph build: two-level counting sort ----------------

__global__ __launch_bounds__(256) void k_hist(const int* __restrict__ dst,
                                              int* __restrict__ histT, int e) {
    __shared__ int lh[NBKT];
    int tid = threadIdx.x, k = blockIdx.x;
    if (tid < NBKT) lh[tid] = 0;
    __syncthreads();
    int chunk = (e + NB_S - 1) / NB_S;
    int i0 = k * chunk, i1 = min(i0 + chunk, e);
    for (int i = i0 + tid; i < i1; i += 256) atomicAdd(&lh[dst[i] >> BSH], 1);
    __syncthreads();
    if (tid < NBKT) histT[tid * NB_S + k] = lh[tid];
}

__global__ __launch_bounds__(256) void k_scatter(const int* __restrict__ edges,
                                                 const int* __restrict__ offs,
                                                 int2* __restrict__ staging, int e) {
    __shared__ int cur[NBKT];
    int tid = threadIdx.x, k = blockIdx.x;
    if (tid < NBKT) cur[tid] = offs[tid * NB_S + k];
    __syncthreads();
    int chunk = (e + NB_S - 1) / NB_S;
    int i0 = k * chunk, i1 = min(i0 + chunk, e);
    for (int i = i0 + tid; i < i1; i += 256) {
        int s = edges[i];
        int d = edges[e + i];
        int p = atomicAdd(&cur[d >> BSH], 1);
        staging[p] = make_int2(s, d);
    }
}

__global__ __launch_bounds__(256) void k_bucket_fill(const int2* __restrict__ staging,
        const int* __restrict__ offs, int* __restrict__ rowptr,
        float* __restrict__ invd, int* __restrict__ adj, int n, int e) {
    __shared__ int ldeg[NPB];
    __shared__ int lrow[NPB];
    __shared__ int ps[256];
    __shared__ int lseg[SEG_CAP];
    int tid = threadIdx.x, b = blockIdx.x;
    int n0 = b << BSH;
    int nn = min(NPB, n - n0);
    int segBeg = offs[b * NB_S];
    int segEnd = (b == NBKT - 1) ? e : offs[(b + 1) * NB_S];

    ldeg[tid] = 0; ldeg[tid + 256] = 0;
    __syncthreads();
    for (int i = segBeg + tid; i < segEnd; i += 256)
        atomicAdd(&ldeg[staging[i].y - n0], 1);
    __syncthreads();

    int a0 = ldeg[2 * tid], a1 = ldeg[2 * tid + 1];
    int s = a0 + a1;
    ps[tid] = s;
    __syncthreads();
    for (int off = 1; off < 256; off <<= 1) {
        int t = (tid >= off) ? ps[tid - off] : 0;
        __syncthreads();
        ps[tid] += t;
        __syncthreads();
    }
    int excl = ps[tid] - s;
    lrow[2 * tid] = excl;
    lrow[2 * tid + 1] = excl + a0;
    __syncthreads();

    for (int j = tid; j < nn; j += 256) {
        rowptr[n0 + j] = segBeg + lrow[j];
        int d = ldeg[j];
        invd[n0 + j] = (d > 0) ? (1.0f / (float)d) : 0.0f;
    }
    if (b == NBKT - 1 && tid == 0) rowptr[n] = e;
    __syncthreads();

    for (int i = segBeg + tid; i < segEnd; i += 256) {
        int2 ed = staging[i];
        int p = atomicAdd(&lrow[ed.y - n0], 1);
        if (p < SEG_CAP) lseg[p] = ed.x;
        else adj[segBeg + p] = ed.x;
    }
    __syncthreads();

    int m = segEnd - segBeg; if (m > SEG_CAP) m = SEG_CAP;
    for (int p = tid; p < m; p += 256) adj[segBeg + p] = lseg[p];
}

// ---------------- aggregation: quad-gather ----------------
// One wave per node. lane = (quad = lane>>4, seg = lane&15). Each wave load
// instruction covers 4 edges x 256 B (lane loads float4 of row adj[e+4c+quad],
// feature segment seg*4). 8 loads in flight = 32 edges/iter with 4x fewer
// VMEM+VALU instructions per edge than the lane-per-feature version.
// Per-quad float4 accumulators; __shfl_xor(16,32) reduces across quads.

__device__ __forceinline__ float4 ld4c(const float* p) { return *(const float4*)p; }

__global__ __launch_bounds__(256) void k_aggregate(const int* __restrict__ rowptr,
        const int* __restrict__ adj, const float* __restrict__ invd,
        const float* __restrict__ hin, float* __restrict__ agg, int n) {
    int wid = threadIdx.x >> 6, lane = threadIdx.x & 63;
    int node = blockIdx.x * 4 + wid;
    if (node >= n) return;
    int beg = rowptr[node], end = rowptr[node + 1];
    int quad = lane >> 4;
    int cseg = (lane & 15) << 2;
    float ax = 0.f, ay = 0.f, az = 0.f, aw = 0.f;
    for (int e = beg; e < end; e += 32) {
        int idx[8];
        #pragma unroll
        for (int c = 0; c < 8; ++c) {
            int ee = e + 4 * c + quad;
            idx[c] = adj[ee < end ? ee : end - 1];
        }
        float4 v[8];
        #pragma unroll
        for (int c = 0; c < 8; ++c)
            v[c] = ld4c(&hin[(size_t)idx[c] * HID_C + cseg]);
        #pragma unroll
        for (int c = 0; c < 8; ++c) {
            bool ok = (e + 4 * c + quad) < end;
            ax += ok ? v[c].x : 0.f;
            ay += ok ? v[c].y : 0.f;
            az += ok ? v[c].z : 0.f;
            aw += ok ? v[c].w : 0.f;
        }
    }
    // reduce the 4 quad-partials (lanes with equal seg, differing quad bits)
    ax += __shfl_xor(ax, 16, 64); ay += __shfl_xor(ay, 16, 64);
    az += __shfl_xor(az, 16, 64); aw += __shfl_xor(aw, 16, 64);
    ax += __shfl_xor(ax, 32, 64); ay += __shfl_xor(ay, 32, 64);
    az += __shfl_xor(az, 32, 64); aw += __shfl_xor(aw, 32, 64);
    if (quad == 0) {
        float s = invd[node];
        float4 o;
        o.x = ax * s; o.y = ay * s; o.z = az * s; o.w = aw * s;
        *(float4*)&agg[(size_t)node * HID_C + cseg] = o;
    }
}

// ---------------- tiled GEMM (64 rows x 64 cols, K=128, thread = 4x4 tile) ----
// R4/R9 PROVEN ARTIFACT — byte-identical. 65 us pred GEMM, 44 MB fetch,
// VGPR 92, no scratch. Every structural deviation tried (R5-R10) triggered a
// hipcc scratch pathology (1.5-6.3 GB HBM traffic/dispatch, VALUBusy ~1%).
// DO NOT MODIFY THIS KERNEL.
// MODE 0: encoder  MODE 1: layer  MODE 2: pred (fused @W2+b2)

__device__ __forceinline__ float4 ld4(const float* p) { return *(const float4*)p; }

template<int MODE>
__global__ __launch_bounds__(256, 2) void k_gemm(
    const float* __restrict__ A1, const float* __restrict__ A2,
    const int* __restrict__ pidx,
    const float* __restrict__ Ws1, const float* __restrict__ Ws2,
    const float* __restrict__ bias, const float* __restrict__ W2p,
    const float* __restrict__ b2p,
    float* __restrict__ outp, int nrows)
{
    __shared__ float AT[128 * 64];   // 32 KB, transposed+swizzled
    __shared__ float Wm[128 * 64];   // 32 KB, k-major
    const int t = threadIdx.x;
    const int g0 = blockIdx.x * 64;

    #pragma unroll
    for (int p = 0; p < 8; ++p) {
        int k = p * 16 + (t >> 4);
        int c4 = (t & 15) * 4;
        float4 wv;
        if (MODE == 1) wv = (k < 64) ? ld4(Ws1 + k * 64 + c4) : ld4(Ws2 + (k - 64) * 64 + c4);
        else           wv = ld4(Ws1 + k * 64 + c4);
        *(float4*)&Wm[k * 64 + c4] = wv;
    }
    #pragma unroll
    for (int p = 0; p < 8; ++p) {
        int r = p * 8 + (t >> 5);
        int c = t & 31;
        int g = g0 + r; if (g > nrows - 1) g = nrows - 1;
        const float* ptr;
        if (MODE == 0)      ptr = A1 + (size_t)g * 128 + c * 4;
        else if (MODE == 1) ptr = (c < 16) ? (A1 + (size_t)g * 64 + c * 4)
                                           : (A2 + (size_t)g * 64 + (c - 16) * 4);
        else { int idx = pidx[2 * g + (c >> 4)]; ptr = A1 + (size_t)idx * 64 + (c & 15) * 4; }
        float4 av = ld4(ptr);
        int rs = r ^ ((c & 15) * 4);
        int base = c * 256 + rs;
        AT[base      ] = av.x;
        AT[base +  64] = av.y;
        AT[base + 128] = av.z;
        AT[base + 192] = av.w;
    }
    __syncthreads();

    const int tc = t & 15, tr = t >> 4;
    const int tc4 = tc * 4, tr4 = tr * 4;
    float4 acc0 = {0, 0, 0, 0}, acc1 = acc0, acc2 = acc0, acc3 = acc0;

    #pragma unroll 4
    for (int kc = 0; kc < 32; ++kc) {
        int abase = kc * 256 + (tr4 ^ ((kc & 15) * 4));
        int wbase = kc * 256 + tc4;
        #pragma unroll
        for (int i = 0; i < 4; ++i) {
            float4 aw = ld4(&AT[abase + i * 64]);
            float4 ww = ld4(&Wm[wbase + i * 64]);
            acc0.x = fmaf(aw.x, ww.x, acc0.x); acc0.y = fmaf(aw.x, ww.y, acc0.y);
            acc0.z = fmaf(aw.x, ww.z, acc0.z); acc0.w = fmaf(aw.x, ww.w, acc0.w);
            acc1.x = fmaf(aw.y, ww.x, acc1.x); acc1.y = fmaf(aw.y, ww.y, acc1.y);
            acc1.z = fmaf(aw.y, ww.z, acc1.z); acc1.w = fmaf(aw.y, ww.w, acc1.w);
            acc2.x = fmaf(aw.z, ww.x, acc2.x); acc2.y = fmaf(aw.z, ww.y, acc2.y);
            acc2.z = fmaf(aw.z, ww.z, acc2.z); acc2.w = fmaf(aw.z, ww.w, acc2.w);
            acc3.x = fmaf(aw.w, ww.x, acc3.x); acc3.y = fmaf(aw.w, ww.y, acc3.y);
            acc3.z = fmaf(aw.w, ww.z, acc3.z); acc3.w = fmaf(aw.w, ww.w, acc3.w);
        }
    }

    float4 bv = ld4(bias + tc4);
    float4 accs[4] = {acc0, acc1, acc2, acc3};
    if (MODE == 2) {
        float4 w2 = ld4(W2p + tc4);
        float bb = b2p[0];
        #pragma unroll
        for (int i = 0; i < 4; ++i) {
            float zx = fmaxf(accs[i].x + bv.x, 0.f);
            float zy = fmaxf(accs[i].y + bv.y, 0.f);
            float zz = fmaxf(accs[i].z + bv.z, 0.f);
            float zw = fmaxf(accs[i].w + bv.w, 0.f);
            float v = zx * w2.x + zy * w2.y + zz * w2.z + zw * w2.w;
            v += __shfl_down(v, 8, 64);
            v += __shfl_down(v, 4, 64);
            v += __shfl_down(v, 2, 64);
            v += __shfl_down(v, 1, 64);
            if (tc == 0) {
                int g = g0 + tr4 + i;
                if (g < nrows) outp[g] = v + bb;
            }
        }
    } else {
        #pragma unroll
        for (int i = 0; i < 4; ++i) {
            int g = g0 + tr4 + i;
            if (g < nrows) {
                float4 o;
                o.x = fmaxf(accs[i].x + bv.x, 0.f);
                o.y = fmaxf(accs[i].y + bv.y, 0.f);
                o.z = fmaxf(accs[i].z + bv.z, 0.f);
                o.w = fmaxf(accs[i].w + bv.w, 0.f);
                *(float4*)&outp[(size_t)g * 64 + tc4] = o;
            }
        }
    }
}

// ---------------- launch ----------------

extern "C" void kernel_launch(void* const* d_in, const int* in_sizes, int n_in,
                              void* d_out, int out_size, void* d_ws, size_t ws_size,
                              hipStream_t stream) {
    const float* x    = (const float*)d_in[0];
    const int*   edges= (const int*)d_in[1];
    const int*   pair = (const int*)d_in[2];
    const float* encW = (const float*)d_in[3];
    const float* encb = (const float*)d_in[4];
    const float* Wl   = (const float*)d_in[5];
    const float* bl   = (const float*)d_in[6];
    const float* Wr   = (const float*)d_in[7];
    const float* W1   = (const float*)d_in[8];
    const float* b1   = (const float*)d_in[9];
    const float* W2   = (const float*)d_in[10];
    const float* b2   = (const float*)d_in[11];
    float* out = (float*)d_out;

    const int N = N_NODES_C, E = N_EDGES_C, P = N_PAIRS_C;
    const int* dst = edges + E;
    const int M = NBKT * NB_S;

    char* w = (char*)d_ws;
    auto alloc = [&](size_t bytes) { char* p = w; w += (bytes + 255) & ~(size_t)255; return p; };
    int*   rowptr = (int*)alloc((size_t)(N + 1) * 4);
    int*   histT  = (int*)alloc((size_t)M * 4);
    int*   offs   = (int*)alloc((size_t)M * 4);
    int*   bsums  = (int*)alloc(128 * 4);
    float* invd   = (float*)alloc((size_t)N * 4);
    int*   adj    = (int*)alloc((size_t)E * 4);
    float* h0     = (float*)alloc((size_t)N * HID_C * 4);
    float* h1     = (float*)alloc((size_t)N * HID_C * 4);
    float* agg    = (float*)alloc((size_t)N * HID_C * 4);
    int2*  staging= (int2*)agg;   // alias: dead before agg is live

    int nscan = (M + SCAN_ELEMS - 1) / SCAN_ELEMS;

    hipLaunchKernelGGL(k_hist, dim3(NB_S), dim3(256), 0, stream, dst, histT, E);
    hipLaunchKernelGGL(k_scan_partial, dim3(nscan), dim3(SCAN_TPB), 0, stream, histT, offs, bsums, M);
    hipLaunchKernelGGL(k_scan_blocks, dim3(1), dim3(128), 0, stream, bsums, nscan);
    hipLaunchKernelGGL(k_scan_addg, dim3((M + 255) / 256), dim3(256), 0, stream, offs, bsums, M);
    hipLaunchKernelGGL(k_scatter, dim3(NB_S), dim3(256), 0, stream, edges, offs, staging, E);
    hipLaunchKernelGGL(k_bucket_fill, dim3(NBKT), dim3(256), 0, stream, staging, offs, rowptr, invd, adj, N, E);

    const int NB_N = (N + 63) / 64;
    const int NB_P = (P + 63) / 64;

    k_gemm<0><<<dim3(NB_N), dim3(256), 0, stream>>>(
        x, nullptr, nullptr, encW, nullptr, encb, nullptr, nullptr, h0, N);

    float* hc = h0; float* hn = h1;
    for (int l = 0; l < 3; l++) {
        hipLaunchKernelGGL(k_aggregate, dim3((N + 3) / 4), dim3(256), 0, stream,
                           rowptr, adj, invd, hc, agg, N);
        k_gemm<1><<<dim3(NB_N), dim3(256), 0, stream>>>(
            agg, hc, nullptr, Wl + (size_t)l * 64 * 64, Wr + (size_t)l * 64 * 64,
            bl + (size_t)l * 64, nullptr, nullptr, hn, N);
        float* tswap = hc; hc = hn; hn = tswap;
    }

    k_gemm<2><<<dim3(NB_P), dim3(256), 0, stream>>>(
        hc, nullptr, pair, W1, nullptr, b1, W2, b2, out, P);
}